// Round 3
// baseline (611.122 us; speedup 1.0000x reference)
//
#include <hip/hip_runtime.h>

// Problem constants: EMB=64, HEADS=8, TOK=10, CAP=32 (tables 63 rows),
// dim_q=dim_k=4116, dim_i=20, dim_h=dim_w=dim_d=16. S=4096; dim_q=20+4096.
//
// out[h][q][k] fp32:
//   q <  20           : 0
//   q >= 20, k <  20  : cross_s[h][k] * 0.125
//   q >= 20, k >= 20  : (row_s[h][i][l] + col_s[h][j][m] + dep_s[h][kk][n]) * 0.125/3
//     r=q-20: i=r>>8, j=(r>>4)&15, kk=r&15;  c=k-20: l=c>>8, m=(c>>4)&15, n=c&15
//
// tabs (ws floats): [0,160) cross (pre-scaled 0.125)
//                   [160,2208) row_s, [2208,4256) col_s, [4256,6304) dep_s
//                   (each 8x16x16, pre-scaled 0.125/3)

#define EMB 64
#define NHEADS 8
#define DIM_I 20
#define DIM_Q 4116
#define NCHUNK 1029          // float4 per row (4116*4 B, 16B-aligned)
#define OFF_ROW 160
#define OFF_COL (160 + 2048)
#define OFF_DEP (160 + 4096)
#define N_DOTS 6304          // 160 + 3*2048

typedef float v4f __attribute__((ext_vector_type(4)));

// One wave per dot product: lane c multiplies element c, butterfly-reduce.
__global__ __launch_bounds__(256) void tables_kernel(
    const float* __restrict__ enc_cross,  // [20][64]
    const float* __restrict__ enc_h,      // [63][64]
    const float* __restrict__ enc_w,
    const float* __restrict__ enc_d,
    const float* __restrict__ w_cross,    // [8][64]
    const float* __restrict__ w_h,
    const float* __restrict__ w_w,
    const float* __restrict__ w_d,
    float* __restrict__ tabs)
{
    const int wid  = (blockIdx.x * 256 + threadIdx.x) >> 6;
    const int lane = threadIdx.x & 63;
    if (wid >= N_DOTS) return;

    const float* wv;
    const float* ev;
    float scale;
    int outidx;
    if (wid < 160) {
        const int h = wid / DIM_I;
        const int n = wid % DIM_I;
        wv = w_cross + h * EMB;
        ev = enc_cross + n * EMB;
        scale = 0.125f;
        outidx = wid;
    } else {
        const int u = wid - 160;
        const int table = u >> 11;      // 0=row 1=col 2=dep
        const int v = u & 2047;
        const int h = v >> 8;
        const int i = (v >> 4) & 15;
        const int l = v & 15;
        const int ridx = l - i + 31;    // in [16,46], never clipped for dim 16
        if (table == 0)      { wv = w_h + h * EMB; ev = enc_h + ridx * EMB; }
        else if (table == 1) { wv = w_w + h * EMB; ev = enc_w + ridx * EMB; }
        else                 { wv = w_d + h * EMB; ev = enc_d + ridx * EMB; }
        scale = 0.125f / 3.0f;
        outidx = 160 + u;
    }

    float p = wv[lane] * ev[lane];
    #pragma unroll
    for (int off = 32; off >= 1; off >>= 1)
        p += __shfl_xor(p, off, 64);
    if (lane == 0) tabs[outidx] = p * scale;
}

// grid (258, 8): blockIdx.x<256 -> (i,j) unit writing 16 contiguous rows;
// blockIdx.x in {256,257} -> half of the 20 zero rows for this head.
__global__ __launch_bounds__(256) void fill_kernel(
    const float* __restrict__ tabs, float* __restrict__ out)
{
    const int h   = blockIdx.y;
    const int r   = blockIdx.x;
    const int tid = threadIdx.x;
    float* outh = out + (size_t)h * DIM_Q * DIM_Q;

    if (r >= 256) {
        // zero rows q=0..19: 20*1029 = 20580 float4 chunks, contiguous; half each
        v4f* p = (v4f*)outh + (size_t)(r - 256) * 10290;
        const v4f z = {0.f, 0.f, 0.f, 0.f};
        for (int t = tid; t < 10290; t += 256)
            __builtin_nontemporal_store(z, p + t);
        return;
    }

    __shared__ __align__(16) float Base[256];   // Base[l*16+m] = row_s[i][l]+col_s[j][m]
    __shared__ __align__(16) float dep[256];    // dep[kk*16+n]
    __shared__ float cross20[DIM_I];

    const int i = r >> 4;
    const int j = r & 15;
    Base[tid] = tabs[OFF_ROW + h * 256 + i * 16 + (tid >> 4)]
              + tabs[OFF_COL + h * 256 + j * 16 + (tid & 15)];
    dep[tid] = tabs[OFF_DEP + h * 256 + tid];
    if (tid < DIM_I) cross20[tid] = tabs[h * DIM_I + tid];
    __syncthreads();

    const int q0 = DIM_I + i * 256 + j * 16;
    for (int kk = 0; kk < 16; ++kk) {
        v4f* rowp = (v4f*)(outh + (size_t)(q0 + kk) * DIM_Q);
        const float* ds = dep + kk * 16;
        for (int t = tid; t < NCHUNK; t += 256) {
            v4f v;
            if (t < 5) {
                const int k0 = 4 * t;
                v.x = cross20[k0 + 0];
                v.y = cross20[k0 + 1];
                v.z = cross20[k0 + 2];
                v.w = cross20[k0 + 3];
            } else {
                const int c0 = 4 * t - DIM_I;          // >=0, multiple of 4
                const float b = Base[c0 >> 4];
                const v4f d = *(const v4f*)(ds + (c0 & 15)); // 16B-aligned
                v = d + b;
            }
            __builtin_nontemporal_store(v, rowp + t);
        }
    }
}

extern "C" void kernel_launch(void* const* d_in, const int* in_sizes, int n_in,
                              void* d_out, int out_size, void* d_ws, size_t ws_size,
                              hipStream_t stream)
{
    const float* enc_cross = (const float*)d_in[0];
    const float* enc_h     = (const float*)d_in[1];
    const float* enc_w     = (const float*)d_in[2];
    const float* enc_d     = (const float*)d_in[3];
    const float* w_cross   = (const float*)d_in[4];
    const float* w_h       = (const float*)d_in[5];
    const float* w_w       = (const float*)d_in[6];
    const float* w_d       = (const float*)d_in[7];

    float* tabs = (float*)d_ws;   // 6304 floats

    tables_kernel<<<dim3((N_DOTS * 64 + 255) / 256), dim3(256), 0, stream>>>(
        enc_cross, enc_h, enc_w, enc_d, w_cross, w_h, w_w, w_d, tabs);

    fill_kernel<<<dim3(258, NHEADS), dim3(256), 0, stream>>>(
        tabs, (float*)d_out);
}

// Round 4
// 569.174 us; speedup vs baseline: 1.0737x; 1.0737x over previous
//
#include <hip/hip_runtime.h>

// EMB=64, HEADS=8, TOK=10, CAP=32 (63-row tables), dim_q=dim_k=4116,
// dim_i=20, dim_h=dim_w=dim_d=16. S=4096; dim_q=20+4096.
//
// out[h][q][k] fp32:
//   q <  20           : 0
//   q >= 20, k <  20  : cross_s[h][k] * 0.125
//   q >= 20, k >= 20  : (row_s[h][i][l] + col_s[h][j][m] + dep_s[h][kk][n]) * (0.125/3)
//     r=q-20: i=r>>8, j=(r>>4)&15, kk=r&15;  c=k-20: l=c>>8, m=(c>>4)&15, n=c&15
//
// Fill strategy: block=(h,i,j) writes 16 contiguous rows (kk=0..15).
// Per wave-instruction the content span c in [s*256,(s+1)*256) has wave-uniform
// l=s; per-lane m=lane>>2, n=4*lane&15 are loop-invariant -> B+C quad lives in
// registers per row; inner loop = ds_read_b32 bcast + 4 adds + store_dwordx4.
//
// tabs (ws floats): [0,160) cross (pre-scaled 0.125)
//                   [160,2208) row_s, [2208,4256) col_s, [4256,6304) dep_s

#define EMB 64
#define NHEADS 8
#define DIM_I 20
#define DIM_Q 4116
#define OFF_ROW 160
#define OFF_COL (160 + 2048)
#define OFF_DEP (160 + 4096)
#define N_DOTS 6304

typedef float v4f __attribute__((ext_vector_type(4)));

// One wave per dot product: lane c multiplies element c, butterfly-reduce.
__global__ __launch_bounds__(256) void tables_kernel(
    const float* __restrict__ enc_cross,  // [20][64]
    const float* __restrict__ enc_h,      // [63][64]
    const float* __restrict__ enc_w,
    const float* __restrict__ enc_d,
    const float* __restrict__ w_cross,    // [8][64]
    const float* __restrict__ w_h,
    const float* __restrict__ w_w,
    const float* __restrict__ w_d,
    float* __restrict__ tabs)
{
    const int wid  = (blockIdx.x * 256 + threadIdx.x) >> 6;
    const int lane = threadIdx.x & 63;
    if (wid >= N_DOTS) return;

    const float* wv;
    const float* ev;
    float scale;
    if (wid < 160) {
        const int h = wid / DIM_I;
        const int n = wid % DIM_I;
        wv = w_cross + h * EMB;
        ev = enc_cross + n * EMB;
        scale = 0.125f;
    } else {
        const int u = wid - 160;
        const int table = u >> 11;      // 0=row 1=col 2=dep
        const int v = u & 2047;
        const int h = v >> 8;
        const int i = (v >> 4) & 15;
        const int l = v & 15;
        const int ridx = l - i + 31;    // in [16,46], never clipped for dim 16
        if (table == 0)      { wv = w_h + h * EMB; ev = enc_h + ridx * EMB; }
        else if (table == 1) { wv = w_w + h * EMB; ev = enc_w + ridx * EMB; }
        else                 { wv = w_d + h * EMB; ev = enc_d + ridx * EMB; }
        scale = 0.125f / 3.0f;
    }

    float p = wv[lane] * ev[lane];
    #pragma unroll
    for (int off = 32; off >= 1; off >>= 1)
        p += __shfl_xor(p, off, 64);
    if (lane == 0) tabs[wid] = p * scale;
}

// grid (258, 8): x<256 -> (i,j) content block (16 rows); x in {256,257} ->
// half of the 20 zero rows for this head.
__global__ __launch_bounds__(256) void fill_kernel(
    const float* __restrict__ tabs, float* __restrict__ out)
{
    const int h   = blockIdx.y;
    const int r   = blockIdx.x;
    const int tid = threadIdx.x;
    float* outh = out + (size_t)h * DIM_Q * DIM_Q;

    if (r >= 256) {
        // zero rows q=0..19: 20*4116/4 = 20580 chunks; half per block
        v4f* p = (v4f*)outh + (size_t)(r - 256) * 10290;
        const v4f z = {0.f, 0.f, 0.f, 0.f};
        for (int t = tid; t < 10290; t += 256) p[t] = z;
        return;
    }

    const int i    = r >> 4;
    const int j    = r & 15;
    const int lane = tid & 63;
    const int wave = tid >> 6;

    __shared__ float A16[16];                 // row_s[h][i][*]
    __shared__ __align__(16) float C[256];    // dep_s[h][*][*]
    if (tid < 16) A16[tid] = tabs[OFF_ROW + h * 256 + i * 16 + tid];
    C[tid] = tabs[OFF_DEP + h * 256 + tid];

    // per-lane loop invariants (global reads, L1-resident)
    const float vB = tabs[OFF_COL + h * 256 + j * 16 + (lane >> 2)];  // col_s[h][j][m(lane)]
    v4f vcross = {0.f, 0.f, 0.f, 0.f};
    if (lane < 5) vcross = *(const v4f*)(tabs + h * DIM_I + 4 * lane);
    __syncthreads();

    const int q0 = DIM_I + i * 256 + j * 16;
    // wave w handles rows kk = 4w .. 4w+3 (contiguous 64 KB run per wave)
    for (int rr = 0; rr < 4; ++rr) {
        const int kk = wave * 4 + rr;
        float* rowp = outh + (size_t)(q0 + kk) * DIM_Q;
        const v4f vC = *(const v4f*)(C + kk * 16 + ((lane * 4) & 15)); // dep quad, n(lane)
        const v4f vBC = vC + vB;
        if (lane < 5) *(v4f*)(rowp + 4 * lane) = vcross;   // k < 20 block
        float* cp = rowp + DIM_I;
        #pragma unroll
        for (int s = 0; s < 16; ++s) {
            const float As = A16[s];          // wave-uniform broadcast
            v4f v = vBC + As;
            *(v4f*)(cp + s * 256 + 4 * lane) = v;
        }
    }
}

extern "C" void kernel_launch(void* const* d_in, const int* in_sizes, int n_in,
                              void* d_out, int out_size, void* d_ws, size_t ws_size,
                              hipStream_t stream)
{
    const float* enc_cross = (const float*)d_in[0];
    const float* enc_h     = (const float*)d_in[1];
    const float* enc_w     = (const float*)d_in[2];
    const float* enc_d     = (const float*)d_in[3];
    const float* w_cross   = (const float*)d_in[4];
    const float* w_h       = (const float*)d_in[5];
    const float* w_w       = (const float*)d_in[6];
    const float* w_d       = (const float*)d_in[7];

    float* tabs = (float*)d_ws;   // 6304 floats

    tables_kernel<<<dim3((N_DOTS * 64 + 255) / 256), dim3(256), 0, stream>>>(
        enc_cross, enc_h, enc_w, enc_d, w_cross, w_h, w_w, w_d, tabs);

    fill_kernel<<<dim3(258, NHEADS), dim3(256), 0, stream>>>(
        tabs, (float*)d_out);
}